// Round 5
// baseline (106.671 us; speedup 1.0000x reference)
//
#include <hip/hip_runtime.h>
#include <math.h>

// DecisionTrees2: out[n, idx] = prod_f softmax((x[n,f]*W + b[f]) / 0.1)[d_f]
// idx = d0*4^7 + ... + d7.  Factor as Phi[hi] * Plo[lo] (4 digits each).
// 512 MiB f32 output => HBM-write bound.
// R5: dispatch reshape. 256 blocks (1/CU), 8 rows/block => 2 MiB contiguous
//     writes per block, ~256 concurrent DRAM streams (was 2048). All row
//     setup precomputed before ONE barrier; store loop is barrier-free
//     (a per-row __syncthreads would drain vmcnt(0) and stall the stream).

typedef float f32x4 __attribute__((ext_vector_type(4)));

#define ROWS_PER_BLOCK 8

__global__ __launch_bounds__(256) void dt2_kernel(const float* __restrict__ x,
                                                  const float* __restrict__ cps,
                                                  float* __restrict__ out) {
    __shared__ float bins[ROWS_PER_BLOCK][8][4];   // [row][feature][bin]
    __shared__ float Phi[ROWS_PER_BLOCK][256];     // hi-product per row

    const int t  = threadIdx.x;
    const int n0 = blockIdx.x * ROWS_PER_BLOCK;

    // --- softmaxes for 8 rows x 8 features (threads 0..63) ---
    if (t < 8 * ROWS_PER_BLOCK) {
        const int r = t >> 3;
        const int f = t & 7;
        const float a = cps[f * 3 + 0];
        const float b = cps[f * 3 + 1];
        const float c = cps[f * 3 + 2];
        // sort 3 values
        const float lo = fminf(a, b), hi = fmaxf(a, b);
        const float c0 = fminf(lo, c);
        const float c2 = fmaxf(hi, c);
        const float c1 = fmaxf(lo, fminf(hi, c));
        // bias = cumsum of [0, -c0, -c1, -c2]
        const float b1 = -c0;
        const float b2 = b1 - c1;
        const float b3 = b2 - c2;
        const float xv = x[(n0 + r) * 8 + f];
        // h = x*W + b, W = [1,2,3,4]
        const float h0 = xv * 1.0f;
        const float h1 = xv * 2.0f + b1;
        const float h2 = xv * 3.0f + b2;
        const float h3 = xv * 4.0f + b3;
        const float m = fmaxf(fmaxf(h0, h1), fmaxf(h2, h3));
        const float e0 = __expf((h0 - m) * 10.0f);
        const float e1 = __expf((h1 - m) * 10.0f);
        const float e2 = __expf((h2 - m) * 10.0f);
        const float e3 = __expf((h3 - m) * 10.0f);
        const float inv = 1.0f / (e0 + e1 + e2 + e3);
        bins[r][f][0] = e0 * inv;
        bins[r][f][1] = e1 * inv;
        bins[r][f][2] = e2 * inv;
        bins[r][f][3] = e3 * inv;
    }
    __syncthreads();

    // --- Phi tables for all rows (features 0..3) ---
    {
        const int d0 = (t >> 6) & 3;
        const int d1 = (t >> 4) & 3;
        const int d2 = (t >> 2) & 3;
        const int d3 = t & 3;
        #pragma unroll
        for (int r = 0; r < ROWS_PER_BLOCK; ++r)
            Phi[r][t] = bins[r][0][d0] * bins[r][1][d1] * bins[r][2][d2] * bins[r][3][d3];
    }
    __syncthreads();

    // --- barrier-free store stream: 8 rows x 256 KiB ---
    const int wid = t >> 6;              // Phi broadcast index base
    const int i4 = (t >> 4) & 3;
    const int i5 = (t >> 2) & 3;
    const int i6 = t & 3;

    for (int r = 0; r < ROWS_PER_BLOCK; ++r) {
        const float p3  = bins[r][4][i4] * bins[r][5][i5] * bins[r][6][i6];
        const float pl0 = p3 * bins[r][7][0];
        const float pl1 = p3 * bins[r][7][1];
        const float pl2 = p3 * bins[r][7][2];
        const float pl3 = p3 * bins[r][7][3];

        f32x4* out4 = (f32x4*)(out + (size_t)(n0 + r) * 65536);
        #pragma unroll
        for (int it0 = 0; it0 < 64; it0 += 8) {
            float ph[8];
            #pragma unroll
            for (int u = 0; u < 8; ++u)
                ph[u] = Phi[r][wid + (it0 + u) * 4];
            #pragma unroll
            for (int u = 0; u < 8; ++u) {
                f32x4 v;
                v.x = ph[u] * pl0;
                v.y = ph[u] * pl1;
                v.z = ph[u] * pl2;
                v.w = ph[u] * pl3;
                __builtin_nontemporal_store(v, &out4[t + (it0 + u) * 256]);
            }
        }
    }
}

extern "C" void kernel_launch(void* const* d_in, const int* in_sizes, int n_in,
                              void* d_out, int out_size, void* d_ws, size_t ws_size,
                              hipStream_t stream) {
    const float* x   = (const float*)d_in[0];
    const float* cps = (const float*)d_in[1];
    float* out = (float*)d_out;
    const int N = in_sizes[0] / 8;  // 2048
    dt2_kernel<<<N / ROWS_PER_BLOCK, 256, 0, stream>>>(x, cps, out);
}